// Round 14
// baseline (755.183 us; speedup 1.0000x reference)
//
#include <hip/hip_runtime.h>

// B=512, V=256, W=64, H=64. Outputs: x_tilde_seq (64,512,256) fp32, h_seq (64,512,64) fp32.
// ONE batch per block; 512 blocks x 512 thr; TARGET 2 blocks/CU (16 waves) via
// __launch_bounds__(512,4): 128-reg budget split as ~80 AGPR (MFMA B-frags: w_ih 64 +
// w_hh 16 — MFMA reads B directly from AGPR) + ~48 arch VGPR (w_w slice 16 + working).
// Cross-block overlap fills the per-phase LDS-latency stalls that capped R12/R13 at 35% VALUBusy.
// Step: P1 wout(VALU)+gates-h(MFMA) | B1 | P2 score half-rows | B2 | P4 r+out_xt+gates-x(MFMA) | B3 | P5 cell | B4.

#define KLOG2E  1.4426950408889634f   // log2(e)
#define K2LOG2E 2.8853900817779268f   // 2*log2(e)

typedef _Float16 h2    __attribute__((ext_vector_type(2)));
typedef __fp16   f16x8 __attribute__((ext_vector_type(8)));
typedef float    f32x4 __attribute__((ext_vector_type(4)));
union H2U { h2 h; unsigned u; };

__device__ __forceinline__ float frcp(float x)  { return __builtin_amdgcn_rcpf(x); }
__device__ __forceinline__ float fexp2(float x) { return __builtin_amdgcn_exp2f(x); }
__device__ __forceinline__ float fsigmoid(float x) { return frcp(1.f + fexp2(-KLOG2E * x)); }
__device__ __forceinline__ float ftanh(float x) { return 1.f - 2.f * frcp(fexp2(K2LOG2E * x) + 1.f); }

__device__ __forceinline__ unsigned pkrtz_u(float a, float b) {
    H2U r; r.h = __builtin_bit_cast(h2, __builtin_amdgcn_cvt_pkrtz(a, b)); return r.u;
}

// LDS layout (float slots) — single batch, 73376 B/block (2 blocks/CU fit 160K)
#define L_E    0                    // E [256][68] fp32 = exp(2*(u_out+b_u))
#define L_PS   17408                // gates [256] (final, r-applied)
#define L_XH   17664                // ex packed h2 [128 u32] (unnormalized)
#define L_EW   17792                // e_w [64]
#define L_HC   17856                // h||c fp32 [128]
#define L_HH   17984                // h packed h2 [32 u32]
#define L_BI   18016                // bias b_ih+b_hh [256]
#define L_WV   18272                // -2*w_v [64]
#define L_WS   18336                // wave e-sums [8]
#define L_TOT  18344                // 73376 bytes

__global__ __launch_bounds__(512, 4) void enc_kernel(
    const float* __restrict__ x,     // (512,256,64)
    const float* __restrict__ w_ih,  // (256,256)
    const float* __restrict__ w_hh,  // (256,64)
    const float* __restrict__ b_ih,  // (256)
    const float* __restrict__ b_hh,  // (256)
    const float* __restrict__ w_v,   // (64)
    const float* __restrict__ w_w,   // (64,128)
    const float* __restrict__ b_w,   // (64)
    const float* __restrict__ w_u,   // (64,64)
    const float* __restrict__ b_u,   // (64)
    float* __restrict__ out_xt,      // (64,512,256)
    float* __restrict__ out_h)       // (64,512,64)
{
    extern __shared__ float lds[];
    float*    E    = lds + L_E;
    float*    ps   = lds + L_PS;
    unsigned* xh   = (unsigned*)(lds + L_XH);
    float*    ewL  = lds + L_EW;
    float*    hc   = lds + L_HC;
    unsigned* hh   = (unsigned*)(lds + L_HH);
    float*    biasL= lds + L_BI;
    float*    wv2L = lds + L_WV;
    float*    wsum = lds + L_WS;

    const int tid  = threadIdx.x;
    const int lane = tid & 63;
    const int wvi  = tid >> 6;            // wave 0..7
    const int b    = blockIdx.x;          // one batch per block

    // ---- persistent MFMA B-fragments (AGPR-resident): wave owns gate rows [wvi*32,+32) ----
    // B[k][col]: col = lane&15 (+16 tile1), k = kk*32 + (lane>>4)*8 + i
    f16x8 wbx0[8], wbx1[8], wbh0[2], wbh1[2];
    {
        const int col0 = wvi*32 + (lane & 15);
        const int col1 = col0 + 16;
        const int kofs = (lane >> 4) * 8;
#pragma unroll
        for (int kk = 0; kk < 8; ++kk) {
            const float* s0 = w_ih + col0*256 + kk*32 + kofs;
            const float* s1 = w_ih + col1*256 + kk*32 + kofs;
            f16x8 a, c;
#pragma unroll
            for (int i = 0; i < 8; ++i) { a[i] = (__fp16)s0[i]; c[i] = (__fp16)s1[i]; }
            wbx0[kk] = a; wbx1[kk] = c;
        }
#pragma unroll
        for (int kk = 0; kk < 2; ++kk) {
            const float* s0 = w_hh + col0*64 + kk*32 + kofs;
            const float* s1 = w_hh + col1*64 + kk*32 + kofs;
            f16x8 a, c;
#pragma unroll
            for (int i = 0; i < 8; ++i) { a[i] = (__fp16)s0[i]; c[i] = (__fp16)s1[i]; }
            wbh0[kk] = a; wbh1[kk] = c;
        }
    }
    // wout identity: w8 = wvi*8 + (lane>>3), kg = lane&7; k = kg*4 + 32m
    const int w8 = wvi*8 + (lane >> 3);
    const int kg = lane & 7;
    float4 www4[4];
#pragma unroll
    for (int m = 0; m < 4; ++m)
        www4[m] = *(const float4*)&w_w[w8*128 + kg*4 + 32*m];
    const float bwr = b_w[w8];
    float Sv = 0.f;
#pragma unroll
    for (int wi = 0; wi < 64; ++wi) Sv += w_v[wi];   // uniform scalar loads
    const float bu_lane = b_u[lane];

    // ---- one-time LDS fills ----
    if (tid < 256) biasL[tid] = b_ih[tid] + b_hh[tid];
    if (tid < 64) wv2L[tid] = -2.f * w_v[tid];
    if (tid < 128) hc[tid] = 0.f;
    if (tid < 32)  hh[tid] = 0u;

    // ---- E init: E[v][w] = exp(2*(x[b,v,:]@w_u[w,:] + b_u[w])); wave covers 32 rows ----
#pragma unroll 1
    for (int half = 0; half < 2; ++half) {
        float4 wu_r[8];
#pragma unroll
        for (int i = 0; i < 8; ++i)
            wu_r[i] = *(const float4*)&w_u[lane*64 + half*32 + 4*i];
        const float* xb = x + b*16384 + half*32;
#pragma unroll 2
        for (int vi = 0; vi < 32; ++vi) {
            int v = __builtin_amdgcn_readfirstlane(wvi*32 + vi);
            const float4* xr = (const float4*)(xb + v*64);
            float acc = 0.f;
#pragma unroll
            for (int i = 0; i < 8; ++i) {
                float4 xx = xr[i]; float4 wu = wu_r[i];
                acc += xx.x*wu.x + xx.y*wu.y + xx.z*wu.z + xx.w*wu.w;
            }
            if (half == 0) E[v*68 + lane] = acc + bu_lane;
            else           E[v*68 + lane] = fexp2(K2LOG2E * (E[v*68 + lane] + acc));
        }
    }
    __syncthreads();

    // ---- P2 identity: v = wvi*32 + (lane&31), half = lane>>5 (halves combined in-wave) ----
    const int  v2   = wvi*32 + (lane & 31);
    const int  hf   = lane >> 5;
    const float* xrow  = x + b*16384 + v2*64;
    const float* Erow  = E + v2*68 + hf*32;
    const float* ewS   = ewL + hf*32;
    const float* wvS   = wv2L + hf*32;
    const float  SvIni = hf ? 0.f : Sv;
    float xcur = xrow[0];

    // MFMA lane roles (A-frag: only mrow==0 rows carry data; 4 lanes load k-chunks)
    const int mrow = lane & 15;
    const int q4   = (lane >> 4) * 4;

    for (int t = 0; t < 64; ++t) {
        // ---- P1: wout (VALU) + gates h-part (MFMA) — both read h(t-1) ----
        f32x4 ah0 = {0.f,0.f,0.f,0.f}, ah1 = {0.f,0.f,0.f,0.f};
        {
            float acc = 0.f;
#pragma unroll
            for (int m = 0; m < 4; ++m) {
                float4 w4 = www4[m];
                float4 hv = *(const float4*)&hc[kg*4 + 32*m];
                acc += hv.x*w4.x + hv.y*w4.y + hv.z*w4.z + hv.w*w4.w;
            }
#pragma unroll
            for (int kk = 0; kk < 2; ++kk) {
                f16x8 a = {};
                if (mrow == 0)
                    a = __builtin_bit_cast(f16x8, *(const uint4*)(hh + kk*16 + q4));
                ah0 = __builtin_amdgcn_mfma_f32_16x16x32_f16(a, wbh0[kk], ah0, 0, 0, 0);
                ah1 = __builtin_amdgcn_mfma_f32_16x16x32_f16(a, wbh1[kk], ah1, 0, 0, 0);
            }
            acc += __shfl_xor(acc, 1, 64);
            acc += __shfl_xor(acc, 2, 64);
            acc += __shfl_xor(acc, 4, 64);
            if (kg == 0) ewL[w8] = fexp2(K2LOG2E * (acc + bwr));
        }
        float xnxt = (t < 63) ? xrow[t + 1] : 0.f;   // prefetch; latency spans B1+P2
        __syncthreads();   // B1

        // ---- P2: score half-row (32 rcp); halves combined via shfl_xor(32) ----
        float exreg;
        {
            float ac0 = SvIni, ac1 = 0.f, ac2 = 0.f, ac3 = 0.f;
#pragma unroll
            for (int q = 0; q < 8; ++q) {
                float4 e4 = *(const float4*)&Erow[4*q];
                float4 c4 = *(const float4*)&ewS[4*q];    // broadcast
                float4 v4 = *(const float4*)&wvS[4*q];    // broadcast
                ac0 += v4.x * frcp(e4.x*c4.x + 1.f);
                ac1 += v4.y * frcp(e4.y*c4.y + 1.f);
                ac2 += v4.z * frcp(e4.z*c4.z + 1.f);
                ac3 += v4.w * frcp(e4.w*c4.w + 1.f);
            }
            float acc = (ac0 + ac1) + (ac2 + ac3);
            acc += __shfl_xor(acc, 32, 64);               // combine w-halves
            float e = fexp2(KLOG2E * acc);   // |score| <= sum|w_v| ~2.6: no max-subtract
            exreg = e * xcur;
            float s = e;                                   // reduce over 32 v (both halves equal)
            s += __shfl_xor(s, 1, 64);  s += __shfl_xor(s, 2, 64);
            s += __shfl_xor(s, 4, 64);  s += __shfl_xor(s, 8, 64);
            s += __shfl_xor(s, 16, 64);
            if (lane == 0) wsum[wvi] = s;
            float ex2 = __shfl_xor(exreg, 1, 64);
            if (hf == 0 && !(lane & 1))
                xh[wvi*16 + (lane >> 1)] = pkrtz_u(exreg, ex2);   // stride-1: conflict-free
        }
        xcur = xnxt;
        __syncthreads();   // B2

        // ---- P4: r; out_xt = r*ex_reg; gates x-part MFMA; ps = r*ax + ah ----
        {
            float r = frcp(((wsum[0] + wsum[1]) + (wsum[2] + wsum[3]))
                         + ((wsum[4] + wsum[5]) + (wsum[6] + wsum[7])));
            if (hf == 0) out_xt[t*131072 + b*256 + v2] = r * exreg;

            f32x4 ax0 = {0.f,0.f,0.f,0.f}, ax1 = {0.f,0.f,0.f,0.f};
#pragma unroll
            for (int kk = 0; kk < 8; ++kk) {
                f16x8 a = {};
                if (mrow == 0)
                    a = __builtin_bit_cast(f16x8, *(const uint4*)(xh + kk*16 + q4));
                ax0 = __builtin_amdgcn_mfma_f32_16x16x32_f16(a, wbx0[kk], ax0, 0, 0, 0);
                ax1 = __builtin_amdgcn_mfma_f32_16x16x32_f16(a, wbx1[kk], ax1, 0, 0, 0);
            }
            // D: col = lane&15 (gate row), row 0 (batch) in reg 0
            if (lane < 16) {
                const int j0 = wvi*32 + lane, j1 = j0 + 16;
                ps[j0] = r*ax0[0] + ah0[0];
                ps[j1] = r*ax1[0] + ah1[0];
            }
        }
        __syncthreads();   // B3

        // ---- P5: LSTM cell (wave 0; other block on the CU fills the gap) ----
        if (wvi == 0) {
            const int k = lane;
            float gi = fsigmoid(biasL[k      ] + ps[k      ]);
            float gf = fsigmoid(biasL[64  + k] + ps[64  + k]);
            float gg = ftanh   (biasL[128 + k] + ps[128 + k]);
            float go = fsigmoid(biasL[192 + k] + ps[192 + k]);
            float cn = gf * hc[64 + k] + gi * gg;
            float hn = go * ftanh(cn);
            hc[k] = hn; hc[64 + k] = cn;
            float hp = __shfl_xor(hn, 1, 64);
            if (!(lane & 1)) hh[k >> 1] = pkrtz_u(hn, hp);
            out_h[t*32768 + b*64 + k] = hn;
        }
        __syncthreads();   // B4
    }
}

extern "C" void kernel_launch(void* const* d_in, const int* in_sizes, int n_in,
                              void* d_out, int out_size, void* d_ws, size_t ws_size,
                              hipStream_t stream) {
    const float* x    = (const float*)d_in[0];
    const float* w_ih = (const float*)d_in[1];
    const float* w_hh = (const float*)d_in[2];
    const float* b_ih = (const float*)d_in[3];
    const float* b_hh = (const float*)d_in[4];
    const float* w_v  = (const float*)d_in[5];
    const float* w_w  = (const float*)d_in[6];
    const float* b_w  = (const float*)d_in[7];
    const float* w_u  = (const float*)d_in[8];
    const float* b_u  = (const float*)d_in[9];

    float* out_xt = (float*)d_out;
    float* out_h  = out_xt + 64*512*256;

    const size_t shbytes = (size_t)L_TOT * sizeof(float);  // 73376 B
    (void)hipFuncSetAttribute((const void*)enc_kernel,
                        hipFuncAttributeMaxDynamicSharedMemorySize, (int)shbytes);
    enc_kernel<<<dim3(512), dim3(512), shbytes, stream>>>(
        x, w_ih, w_hh, b_ih, b_hh, w_v, w_w, b_w, w_u, b_u, out_xt, out_h);
}

// Round 15
// 283.013 us; speedup vs baseline: 2.6684x; 2.6684x over previous
//
#include <hip/hip_runtime.h>

// B=512, V=256, W=64, H=64. Outputs: x_tilde_seq (64,512,256) fp32, h_seq (64,512,64) fp32.
// One block = TWO batches (bA, bA+256); 256 blocks x 512 thr, 1 block/CU, 8 waves.
// R13 structure (4 phases) with RAW barriers: s_waitcnt lgkmcnt(0); s_barrier — no vmcnt(0)
// drain (HIP's __syncthreads drains all global loads/stores at every barrier; our x-prefetch
// and out stores are same-thread/no-readback so the drain is pure critical-path waste).
//   P1: wout (VALU) + gates h-part (4 MFMA) | B1
//   P2: score -> e, ex; wave e-sums; pack unnormalized ex->xh; ex kept in REGISTER | B2
//   P4: rA/rB; out_xt = r*ex_reg; gates x-part (16 MFMA); ps = r*ax+ah | B3
//   P5: cell (2 waves) | B4

#define KLOG2E  1.4426950408889634f   // log2(e)
#define K2LOG2E 2.8853900817779268f   // 2*log2(e)

typedef _Float16 h2    __attribute__((ext_vector_type(2)));
typedef __fp16   f16x8 __attribute__((ext_vector_type(8)));
typedef float    f32x4 __attribute__((ext_vector_type(4)));
union H2U { h2 h; unsigned u; };

__device__ __forceinline__ float frcp(float x)  { return __builtin_amdgcn_rcpf(x); }
__device__ __forceinline__ float fexp2(float x) { return __builtin_amdgcn_exp2f(x); }
__device__ __forceinline__ float fsigmoid(float x) { return frcp(1.f + fexp2(-KLOG2E * x)); }
__device__ __forceinline__ float ftanh(float x) { return 1.f - 2.f * frcp(fexp2(K2LOG2E * x) + 1.f); }

__device__ __forceinline__ unsigned pkrtz_u(float a, float b) {
    H2U r; r.h = __builtin_bit_cast(h2, __builtin_amdgcn_cvt_pkrtz(a, b)); return r.u;
}

// Raw barrier: order LDS (lgkmcnt) but do NOT drain global loads/stores (vmcnt).
// Safe here: all global loads are consumed by the issuing thread (HW scoreboard waits at
// use); all global stores are never read back by the kernel.
#define SYNC_LDS() asm volatile("s_waitcnt lgkmcnt(0)\n\ts_barrier" ::: "memory")

// LDS layout (float slots)
#define L_EA   0                    // E_A [256][68] fp32 = exp(2*(u_out+b_u))
#define L_EB   17408                // E_B [256][68]
#define L_PSA  34816                // gates A [256] (final, r-applied)
#define L_PSB  35072                // gates B [256]
#define L_XHA  35328                // ex packed h2 A [128 u32] (unnormalized)
#define L_XHB  35456
#define L_EWA  35584                // e_w A [64]
#define L_EWB  35648
#define L_HCA  35712                // h||c fp32 A [128]
#define L_HCB  35840
#define L_HHA  35968                // h packed h2 A [32 u32]
#define L_HHB  36000
#define L_BI   36032                // bias b_ih+b_hh [256]
#define L_WV   36288                // -2*w_v [64]
#define L_WS   36352                // wave e-sums [8]: 0-3 = A, 4-7 = B
#define L_TOT  36360                // 145440 bytes <= 160K (1 block/CU)

__global__ __launch_bounds__(512, 2) void enc_kernel(
    const float* __restrict__ x,     // (512,256,64)
    const float* __restrict__ w_ih,  // (256,256)
    const float* __restrict__ w_hh,  // (256,64)
    const float* __restrict__ b_ih,  // (256)
    const float* __restrict__ b_hh,  // (256)
    const float* __restrict__ w_v,   // (64)
    const float* __restrict__ w_w,   // (64,128)
    const float* __restrict__ b_w,   // (64)
    const float* __restrict__ w_u,   // (64,64)
    const float* __restrict__ b_u,   // (64)
    float* __restrict__ out_xt,      // (64,512,256)
    float* __restrict__ out_h)       // (64,512,64)
{
    extern __shared__ float lds[];
    float*    EA   = lds + L_EA;    float*    EB   = lds + L_EB;
    float*    psA  = lds + L_PSA;   float*    psB  = lds + L_PSB;
    unsigned* xhA  = (unsigned*)(lds + L_XHA);
    unsigned* xhB  = (unsigned*)(lds + L_XHB);
    float*    ewA  = lds + L_EWA;   float*    ewB  = lds + L_EWB;
    float*    hcA  = lds + L_HCA;   float*    hcB  = lds + L_HCB;
    unsigned* hhA  = (unsigned*)(lds + L_HHA);
    unsigned* hhB  = (unsigned*)(lds + L_HHB);
    float*    biasL= lds + L_BI;
    float*    wv2L = lds + L_WV;
    float*    wsum = lds + L_WS;

    const int tid  = threadIdx.x;
    const int lane = tid & 63;
    const int wvi  = tid >> 6;            // wave 0..7
    const int bA   = blockIdx.x;
    const int bB   = blockIdx.x + 256;

    // ---- persistent MFMA B-fragments: wave wvi owns gate rows [wvi*32,+32) ----
    // B[k][col]: col = lane&15 (+16 for tile1), k = kk*32 + (lane>>4)*8 + i
    f16x8 wbx0[8], wbx1[8], wbh0[2], wbh1[2];
    {
        const int col0 = wvi*32 + (lane & 15);
        const int col1 = col0 + 16;
        const int kofs = (lane >> 4) * 8;
#pragma unroll
        for (int kk = 0; kk < 8; ++kk) {
            const float* s0 = w_ih + col0*256 + kk*32 + kofs;
            const float* s1 = w_ih + col1*256 + kk*32 + kofs;
            f16x8 a, b;
#pragma unroll
            for (int i = 0; i < 8; ++i) { a[i] = (__fp16)s0[i]; b[i] = (__fp16)s1[i]; }
            wbx0[kk] = a; wbx1[kk] = b;
        }
#pragma unroll
        for (int kk = 0; kk < 2; ++kk) {
            const float* s0 = w_hh + col0*64 + kk*32 + kofs;
            const float* s1 = w_hh + col1*64 + kk*32 + kofs;
            f16x8 a, b;
#pragma unroll
            for (int i = 0; i < 8; ++i) { a[i] = (__fp16)s0[i]; b[i] = (__fp16)s1[i]; }
            wbh0[kk] = a; wbh1[kk] = b;
        }
    }
    // wout: thread (w8 = wvi*8+(lane&7), kg = lane>>3) covers k = kg*4 + 32m (m=0..3)
    const int w8 = wvi*8 + (lane & 7);
    const int kg = lane >> 3;
    float4 www4[4];
#pragma unroll
    for (int m = 0; m < 4; ++m)
        www4[m] = *(const float4*)&w_w[w8*128 + kg*4 + 32*m];
    const float bwr = b_w[w8];
    float Sv = 0.f;
#pragma unroll
    for (int wi = 0; wi < 64; ++wi) Sv += w_v[wi];   // uniform scalar loads
    const float bu_lane = b_u[lane];

    // ---- one-time LDS fills ----
    if (tid < 256) biasL[tid] = b_ih[tid] + b_hh[tid];
    if (tid < 64) wv2L[tid] = -2.f * w_v[tid];
    if (tid < 128) { hcA[tid] = 0.f; hcB[tid] = 0.f; }
    if (tid < 32)  { hhA[tid] = 0u; hhB[tid] = 0u; }

    // ---- E init: E[v][w] = exp(2*(x[b,v,:]@w_u[w,:] + b_u[w])), wave covers 32 rows ----
#pragma unroll 1
    for (int bb = 0; bb < 2; ++bb) {
        float* E = bb ? EB : EA;
        const int b = bb ? bB : bA;
#pragma unroll 1
        for (int half = 0; half < 2; ++half) {
            float4 wu_r[8];
#pragma unroll
            for (int i = 0; i < 8; ++i)
                wu_r[i] = *(const float4*)&w_u[lane*64 + half*32 + 4*i];
            const float* xb = x + b*16384 + half*32;
#pragma unroll 2
            for (int vi = 0; vi < 32; ++vi) {
                int v = __builtin_amdgcn_readfirstlane(wvi*32 + vi);
                const float4* xr = (const float4*)(xb + v*64);
                float acc = 0.f;
#pragma unroll
                for (int i = 0; i < 8; ++i) {
                    float4 xx = xr[i]; float4 wu = wu_r[i];
                    acc += xx.x*wu.x + xx.y*wu.y + xx.z*wu.z + xx.w*wu.w;
                }
                if (half == 0) E[v*68 + lane] = acc + bu_lane;
                else           E[v*68 + lane] = fexp2(K2LOG2E * (E[v*68 + lane] + acc));
            }
        }
    }
    __syncthreads();

    // ---- P2 identity: (xj = tid&255, batch = tid>>8); x_t in a register ----
    const int  xj   = tid & 255;
    const int  bsel = tid >> 8;
    const float* xrow = x + (bsel ? bB : bA)*16384 + xj*64;
    const float* Erow = (bsel ? EB : EA) + xj*68;
    const float* ewX  = bsel ? ewB : ewA;
    unsigned*    xhX  = bsel ? xhB : xhA;
    float xcur = xrow[0];

    // MFMA lane roles (shared by P1 h-part and P4 x-part)
    const int mrow = lane & 15;          // M-row: 0=A, 1=B, 2-15 zero
    const int q4   = (lane >> 4) * 4;    // u32 offset of this lane's k-group

    for (int t = 0; t < 64; ++t) {
        // ---- P1: wout (VALU) + gates h-part (MFMA) — both read h(t-1) ----
        f32x4 ah0 = {0.f,0.f,0.f,0.f}, ah1 = {0.f,0.f,0.f,0.f};
        {
            float accA = 0.f, accB = 0.f;
#pragma unroll
            for (int m = 0; m < 4; ++m) {
                float4 w4 = www4[m];
                float4 hA = *(const float4*)&hcA[kg*4 + 32*m];
                float4 hB = *(const float4*)&hcB[kg*4 + 32*m];
                accA += hA.x*w4.x + hA.y*w4.y + hA.z*w4.z + hA.w*w4.w;
                accB += hB.x*w4.x + hB.y*w4.y + hB.z*w4.z + hB.w*w4.w;
            }
            const unsigned* hsrc = (mrow == 1) ? hhB : hhA;
#pragma unroll
            for (int kk = 0; kk < 2; ++kk) {
                f16x8 a = {};
                if (mrow < 2)
                    a = __builtin_bit_cast(f16x8, *(const uint4*)(hsrc + kk*16 + q4));
                ah0 = __builtin_amdgcn_mfma_f32_16x16x32_f16(a, wbh0[kk], ah0, 0, 0, 0);
                ah1 = __builtin_amdgcn_mfma_f32_16x16x32_f16(a, wbh1[kk], ah1, 0, 0, 0);
            }
#pragma unroll
            for (int off = 8; off <= 32; off <<= 1) {
                accA += __shfl_xor(accA, off, 64);
                accB += __shfl_xor(accB, off, 64);
            }
            if (kg == 0)      ewA[w8] = fexp2(K2LOG2E * (accA + bwr));
            else if (kg == 1) ewB[w8] = fexp2(K2LOG2E * (accB + bwr));
        }
        float xnxt = (t < 63) ? xrow[t + 1] : 0.f;   // prefetch; NOT drained at B1 (raw barrier)
        SYNC_LDS();   // B1

        // ---- P2: score -> e, ex; wave e-sums; pack unnormalized ex (reg-carried) ----
        float exreg;
        {
            float ac0 = 0.f, ac1 = 0.f, ac2 = 0.f, ac3 = 0.f;
#pragma unroll
            for (int q = 0; q < 16; ++q) {
                float4 e4 = *(const float4*)&Erow[4*q];
                float4 c4 = *(const float4*)&ewX[4*q];    // broadcast
                float4 v4 = *(const float4*)&wv2L[4*q];   // broadcast
                ac0 += v4.x * frcp(e4.x*c4.x + 1.f);
                ac1 += v4.y * frcp(e4.y*c4.y + 1.f);
                ac2 += v4.z * frcp(e4.z*c4.z + 1.f);
                ac3 += v4.w * frcp(e4.w*c4.w + 1.f);
            }
            float acc = Sv + ((ac0 + ac1) + (ac2 + ac3));
            float e  = fexp2(KLOG2E * acc);  // |score| <= sum|w_v| ~2.6: no max-subtract
            exreg = e * xcur;
            float s = e;
#pragma unroll
            for (int off = 1; off <= 32; off <<= 1) s += __shfl_xor(s, off, 64);
            if (lane == 0) wsum[wvi] = s;
            float ex2 = __shfl_xor(exreg, 1, 64);
            if (!(lane & 1)) xhX[xj >> 1] = pkrtz_u(exreg, ex2);   // stride-1: conflict-free
        }
        xcur = xnxt;
        SYNC_LDS();   // B2

        // ---- P4: r from wsum; out_xt = r*ex_reg; gates x-part MFMA; ps = r*ax + ah ----
        {
            float rA = frcp((wsum[0] + wsum[1]) + (wsum[2] + wsum[3]));
            float rB = frcp((wsum[4] + wsum[5]) + (wsum[6] + wsum[7]));
            out_xt[t*131072 + (bsel ? bB : bA)*256 + xj] = (bsel ? rB : rA) * exreg;

            f32x4 ax0 = {0.f,0.f,0.f,0.f}, ax1 = {0.f,0.f,0.f,0.f};
            const unsigned* xsrc = (mrow == 1) ? xhB : xhA;
#pragma unroll
            for (int kk = 0; kk < 8; ++kk) {
                f16x8 a = {};
                if (mrow < 2)
                    a = __builtin_bit_cast(f16x8, *(const uint4*)(xsrc + kk*16 + q4));
                ax0 = __builtin_amdgcn_mfma_f32_16x16x32_f16(a, wbx0[kk], ax0, 0, 0, 0);
                ax1 = __builtin_amdgcn_mfma_f32_16x16x32_f16(a, wbx1[kk], ax1, 0, 0, 0);
            }
            // D: col = lane&15 (gate row), rows 0/1 = batch A/B in regs 0/1
            if (lane < 16) {
                const int j0 = wvi*32 + lane, j1 = j0 + 16;
                psA[j0] = rA*ax0[0] + ah0[0];
                psA[j1] = rA*ax1[0] + ah1[0];
                psB[j0] = rB*ax0[1] + ah0[1];
                psB[j1] = rB*ax1[1] + ah1[1];
            }
        }
        SYNC_LDS();   // B3

        // ---- P5: LSTM cell (wave0 = A, wave1 = B); gates already reduced ----
        if (wvi < 2) {
            float*    ps = wvi ? psB : psA;
            float*    hc = wvi ? hcB : hcA;
            unsigned* hh = wvi ? hhB : hhA;
            float*    oh = out_h + t*32768 + (wvi ? bB : bA)*64;
            const int k = lane;
            float gi = fsigmoid(biasL[k      ] + ps[k      ]);
            float gf = fsigmoid(biasL[64  + k] + ps[64  + k]);
            float gg = ftanh   (biasL[128 + k] + ps[128 + k]);
            float go = fsigmoid(biasL[192 + k] + ps[192 + k]);
            float cn = gf * hc[64 + k] + gi * gg;
            float hn = go * ftanh(cn);
            hc[k] = hn; hc[64 + k] = cn;
            float hp = __shfl_xor(hn, 1, 64);
            if (!(lane & 1)) hh[k >> 1] = pkrtz_u(hn, hp);
            oh[k] = hn;
        }
        SYNC_LDS();   // B4
    }
}

extern "C" void kernel_launch(void* const* d_in, const int* in_sizes, int n_in,
                              void* d_out, int out_size, void* d_ws, size_t ws_size,
                              hipStream_t stream) {
    const float* x    = (const float*)d_in[0];
    const float* w_ih = (const float*)d_in[1];
    const float* w_hh = (const float*)d_in[2];
    const float* b_ih = (const float*)d_in[3];
    const float* b_hh = (const float*)d_in[4];
    const float* w_v  = (const float*)d_in[5];
    const float* w_w  = (const float*)d_in[6];
    const float* b_w  = (const float*)d_in[7];
    const float* w_u  = (const float*)d_in[8];
    const float* b_u  = (const float*)d_in[9];

    float* out_xt = (float*)d_out;
    float* out_h  = out_xt + 64*512*256;

    const size_t shbytes = (size_t)L_TOT * sizeof(float);  // 145440 B
    (void)hipFuncSetAttribute((const void*)enc_kernel,
                        hipFuncAttributeMaxDynamicSharedMemorySize, (int)shbytes);
    enc_kernel<<<dim3(256), dim3(512), shbytes, stream>>>(
        x, w_ih, w_hh, b_ih, b_hh, w_v, w_w, b_w, w_u, b_u, out_xt, out_h);
}